// Round 2
// baseline (265.168 us; speedup 1.0000x reference)
//
#include <hip/hip_runtime.h>

#define DEVFN __device__ __forceinline__

constexpr int B = 4, S = 2048, H = 4, DH = 16, D = 64, F = 256;
constexpr int T = B * S;   // 8192 tokens

DEVFN float wave_sum(float v) {
#pragma unroll
    for (int mask = 32; mask >= 1; mask >>= 1)
        v += __shfl_xor(v, mask, 64);
    return v;
}

// ---------------------------------------------------------------- kernel 1
// QKV projection. One wave per token; lane j = h*16+k computes Q/K/V[j].
__global__ __launch_bounds__(256) void k_qkv(
    const float* __restrict__ x,
    const float* __restrict__ wq, const float* __restrict__ bq,
    const float* __restrict__ wk, const float* __restrict__ bk,
    const float* __restrict__ wv, const float* __restrict__ bv,
    float* __restrict__ Q, float* __restrict__ K, float* __restrict__ V)
{
    int wid = threadIdx.x >> 6, lane = threadIdx.x & 63;
    int t = blockIdx.x * 4 + wid;
    int b = t >> 11, s = t & (S - 1);
    int h = lane >> 4, k = lane & 15;

    float xv = x[t * D + lane];
    int wbase = h * (D * DH) + k;
    float qa = bq[lane];
    float ka = bk[lane];
    float va = bv[lane];
#pragma unroll 8
    for (int d = 0; d < D; ++d) {
        float xd = __shfl(xv, d, 64);
        int wi = wbase + d * DH;
        qa = fmaf(xd, wq[wi], qa);
        ka = fmaf(xd, wk[wi], ka);
        va = fmaf(xd, wv[wi], va);
    }
    int off = ((b * H + h) * S + s) * DH + k;
    Q[off] = qa * 0.25f;   // fold 1/sqrt(16) into Q (incl. bias)
    K[off] = ka;
    V[off] = va;
}

// ---------------------------------------------------------------- kernel 2
// Causal flash attention. One wave per query row; lane l owns k = l mod 64
// with an independent online softmax; merged at the end by butterfly.
// 4 rows per block share XOR-swizzled LDS K/V tiles.
__global__ __launch_bounds__(256) void k_attn(
    const float* __restrict__ Q, const float* __restrict__ K,
    const float* __restrict__ V, float* __restrict__ A)
{
    __shared__ float4 Kt[256];   // 64 rows x 4 float4, xor-swizzled
    __shared__ float4 Vt[256];

    int wid = threadIdx.x >> 6, lane = threadIdx.x & 63;
    int pair = blockIdx.x >> 9;              // b*H + h  (0..15)
    int rblk = 511 - (blockIdx.x & 511);     // long rows scheduled first
    int b = pair >> 2, h = pair & 3;
    int row = rblk * 4 + wid;

    const float4* q4 = (const float4*)(Q + (pair * S + row) * DH);
    float4 q0 = q4[0], q1 = q4[1], q2 = q4[2], q3 = q4[3];

    float4 a0 = {0,0,0,0}, a1 = a0, a2 = a0, a3 = a0;
    float m = -INFINITY, sum = 0.f;

    const float4* K4 = (const float4*)(K + pair * S * DH);
    const float4* V4 = (const float4*)(V + pair * S * DH);

    int tid = threadIdx.x;
    int kr = tid >> 2, part = tid & 3;
    int sw = (kr << 2) | (part ^ (kr & 3));  // swizzled stage slot
    int rd_base = lane << 2, lx = lane & 3;

    int ntiles = ((rblk * 4 + 3) >> 6) + 1;
    for (int tt = 0; tt < ntiles; ++tt) {
        int kb = tt * 64;
        __syncthreads();
        Kt[sw] = K4[(kb + kr) * 4 + part];
        Vt[sw] = V4[(kb + kr) * 4 + part];
        __syncthreads();

        int kk = kb + lane;
        if (kk <= row) {
            float4 k0 = Kt[rd_base | (0 ^ lx)];
            float4 k1 = Kt[rd_base | (1 ^ lx)];
            float4 k2 = Kt[rd_base | (2 ^ lx)];
            float4 k3 = Kt[rd_base | (3 ^ lx)];
            float sd;
            sd  = q0.x*k0.x; sd = fmaf(q0.y, k0.y, sd); sd = fmaf(q0.z, k0.z, sd); sd = fmaf(q0.w, k0.w, sd);
            sd = fmaf(q1.x, k1.x, sd); sd = fmaf(q1.y, k1.y, sd); sd = fmaf(q1.z, k1.z, sd); sd = fmaf(q1.w, k1.w, sd);
            sd = fmaf(q2.x, k2.x, sd); sd = fmaf(q2.y, k2.y, sd); sd = fmaf(q2.z, k2.z, sd); sd = fmaf(q2.w, k2.w, sd);
            sd = fmaf(q3.x, k3.x, sd); sd = fmaf(q3.y, k3.y, sd); sd = fmaf(q3.z, k3.z, sd); sd = fmaf(q3.w, k3.w, sd);

            if (sd > m) {                      // rare rescale path
                float sc = __expf(m - sd);
                sum *= sc;
                a0.x *= sc; a0.y *= sc; a0.z *= sc; a0.w *= sc;
                a1.x *= sc; a1.y *= sc; a1.z *= sc; a1.w *= sc;
                a2.x *= sc; a2.y *= sc; a2.z *= sc; a2.w *= sc;
                a3.x *= sc; a3.y *= sc; a3.z *= sc; a3.w *= sc;
                m = sd;
            }
            float p = __expf(sd - m);
            sum += p;
            float4 v0 = Vt[rd_base | (0 ^ lx)];
            float4 v1 = Vt[rd_base | (1 ^ lx)];
            float4 v2 = Vt[rd_base | (2 ^ lx)];
            float4 v3 = Vt[rd_base | (3 ^ lx)];
            a0.x = fmaf(p, v0.x, a0.x); a0.y = fmaf(p, v0.y, a0.y); a0.z = fmaf(p, v0.z, a0.z); a0.w = fmaf(p, v0.w, a0.w);
            a1.x = fmaf(p, v1.x, a1.x); a1.y = fmaf(p, v1.y, a1.y); a1.z = fmaf(p, v1.z, a1.z); a1.w = fmaf(p, v1.w, a1.w);
            a2.x = fmaf(p, v2.x, a2.x); a2.y = fmaf(p, v2.y, a2.y); a2.z = fmaf(p, v2.z, a2.z); a2.w = fmaf(p, v2.w, a2.w);
            a3.x = fmaf(p, v3.x, a3.x); a3.y = fmaf(p, v3.y, a3.y); a3.z = fmaf(p, v3.z, a3.z); a3.w = fmaf(p, v3.w, a3.w);
        }
    }

    // ---- merge 64 per-lane partial softmaxes
    float M = m;
#pragma unroll
    for (int mask = 32; mask >= 1; mask >>= 1)
        M = fmaxf(M, __shfl_xor(M, mask, 64));
    float w = __expf(m - M);   // lanes that saw nothing: exp(-inf)=0
    sum *= w;
    a0.x *= w; a0.y *= w; a0.z *= w; a0.w *= w;
    a1.x *= w; a1.y *= w; a1.z *= w; a1.w *= w;
    a2.x *= w; a2.y *= w; a2.z *= w; a2.w *= w;
    a3.x *= w; a3.y *= w; a3.z *= w; a3.w *= w;
#pragma unroll
    for (int mask = 32; mask >= 1; mask >>= 1) {
        sum  += __shfl_xor(sum,  mask, 64);
        a0.x += __shfl_xor(a0.x, mask, 64); a0.y += __shfl_xor(a0.y, mask, 64);
        a0.z += __shfl_xor(a0.z, mask, 64); a0.w += __shfl_xor(a0.w, mask, 64);
        a1.x += __shfl_xor(a1.x, mask, 64); a1.y += __shfl_xor(a1.y, mask, 64);
        a1.z += __shfl_xor(a1.z, mask, 64); a1.w += __shfl_xor(a1.w, mask, 64);
        a2.x += __shfl_xor(a2.x, mask, 64); a2.y += __shfl_xor(a2.y, mask, 64);
        a2.z += __shfl_xor(a2.z, mask, 64); a2.w += __shfl_xor(a2.w, mask, 64);
        a3.x += __shfl_xor(a3.x, mask, 64); a3.y += __shfl_xor(a3.y, mask, 64);
        a3.z += __shfl_xor(a3.z, mask, 64); a3.w += __shfl_xor(a3.w, mask, 64);
    }
    if (lane == 0) {
        float inv = 1.f / sum;
        a0.x *= inv; a0.y *= inv; a0.z *= inv; a0.w *= inv;
        a1.x *= inv; a1.y *= inv; a1.z *= inv; a1.w *= inv;
        a2.x *= inv; a2.y *= inv; a2.z *= inv; a2.w *= inv;
        a3.x *= inv; a3.y *= inv; a3.z *= inv; a3.w *= inv;
        float4* Ap = (float4*)(A + (b * S + row) * D + h * DH);
        Ap[0] = a0; Ap[1] = a1; Ap[2] = a2; Ap[3] = a3;
    }
}

// ---------------------------------------------------------------- kernel 3
// Out-projection + bias + residual + LayerNorm1. One wave per token.
__global__ __launch_bounds__(256) void k_oproj(
    const float* __restrict__ A, const float* __restrict__ x,
    const float* __restrict__ wo, const float* __restrict__ bo,
    const float* __restrict__ g, const float* __restrict__ bb,
    float* __restrict__ R1)
{
    int wid = threadIdx.x >> 6, j = threadIdx.x & 63;
    int t = blockIdx.x * 4 + wid;
    float a = A[t * D + j];
    float o = bo[j] + x[t * D + j];
#pragma unroll 8
    for (int d = 0; d < D; ++d) {
        float ad = __shfl(a, d, 64);
        o = fmaf(ad, wo[d * D + j], o);
    }
    float mu = wave_sum(o) * (1.f / 64.f);
    float dif = o - mu;
    float var = wave_sum(dif * dif) * (1.f / 64.f);
    float r = dif * rsqrtf(var + 1e-5f) * g[j] + bb[j];
    R1[t * D + j] = r;
}

// ---------------------------------------------------------------- kernel 4
// FFN (relu(x@w1+b1)@w2+b2) + residual + LayerNorm2 -> fp32 out.
// One block (256 threads) per token.
__global__ __launch_bounds__(256) void k_ffn(
    const float* __restrict__ R1,
    const float* __restrict__ w1, const float* __restrict__ b1,
    const float* __restrict__ w2, const float* __restrict__ b2,
    const float* __restrict__ g, const float* __restrict__ bb,
    float* __restrict__ out)
{
    __shared__ float xr[64];
    __shared__ float hh[256];
    __shared__ float part[4][64];
    int t = blockIdx.x, tid = threadIdx.x;
    if (tid < 64) xr[tid] = R1[t * D + tid];
    __syncthreads();

    float ha = b1[tid];
#pragma unroll 8
    for (int d = 0; d < D; ++d)
        ha = fmaf(xr[d], w1[d * F + tid], ha);
    hh[tid] = fmaxf(ha, 0.f);
    __syncthreads();

    int p = tid >> 6, j = tid & 63;
    float pa = 0.f;
#pragma unroll 8
    for (int f0 = 0; f0 < 64; ++f0) {
        int f = p * 64 + f0;
        pa = fmaf(hh[f], w2[f * D + j], pa);
    }
    part[p][j] = pa;
    __syncthreads();

    if (tid < 64) {
        float y = part[0][j] + part[1][j] + part[2][j] + part[3][j]
                + b2[j] + xr[j];
        float mu = wave_sum(y) * (1.f / 64.f);
        float dif = y - mu;
        float var = wave_sum(dif * dif) * (1.f / 64.f);
        float r = dif * rsqrtf(var + 1e-5f) * g[j] + bb[j];
        out[t * D + j] = r;
    }
}

// ----------------------------------------------------------------
extern "C" void kernel_launch(void* const* d_in, const int* in_sizes, int n_in,
                              void* d_out, int out_size, void* d_ws, size_t ws_size,
                              hipStream_t stream)
{
    const float* x   = (const float*)d_in[0];
    const float* wq  = (const float*)d_in[1];
    const float* bq  = (const float*)d_in[2];
    const float* wk  = (const float*)d_in[3];
    const float* bk  = (const float*)d_in[4];
    const float* wv  = (const float*)d_in[5];
    const float* bv  = (const float*)d_in[6];
    const float* wo  = (const float*)d_in[7];
    const float* bo  = (const float*)d_in[8];
    const float* g1  = (const float*)d_in[9];
    const float* be1 = (const float*)d_in[10];
    const float* w1  = (const float*)d_in[11];
    const float* b1  = (const float*)d_in[12];
    const float* w2  = (const float*)d_in[13];
    const float* b2  = (const float*)d_in[14];
    const float* g2  = (const float*)d_in[15];
    const float* be2 = (const float*)d_in[16];

    float* ws = (float*)d_ws;
    float* Q  = ws;             // [B,H,S,16]
    float* K  = Q + T * D;      // [B,H,S,16]
    float* V  = K + T * D;      // [B,H,S,16]
    float* A  = V + T * D;      // [B,S,64]  (head-concat layout)
    float* R1 = A + T * D;      // [B,S,64]  post-LN1

    k_qkv <<<T / 4, 256, 0, stream>>>(x, wq, bq, wk, bk, wv, bv, Q, K, V);
    k_attn<<<(B * H) * (S / 4), 256, 0, stream>>>(Q, K, V, A);
    k_oproj<<<T / 4, 256, 0, stream>>>(A, x, wo, bo, g1, be1, R1);
    k_ffn <<<T, 256, 0, stream>>>(R1, w1, b1, w2, b2, g2, be2, (float*)d_out);
}

// Round 3
// 115.718 us; speedup vs baseline: 2.2915x; 2.2915x over previous
//
#include <hip/hip_runtime.h>

#define DEVFN __device__ __forceinline__

constexpr int B = 4, S = 2048, H = 4, DH = 16, D = 64, F = 256;
constexpr int T = B * S;   // 8192 tokens

DEVFN float wave_sum(float v) {
#pragma unroll
    for (int mask = 32; mask >= 1; mask >>= 1)
        v += __shfl_xor(v, mask, 64);
    return v;
}

// ---------------------------------------------------------------- kernel 1
// QKV projection, 16 tokens per block (weights read once per 16 tokens).
// Thread (g, j): column j = h*16+k, tokens 4g..4g+3... (strided g*4+i).
__global__ __launch_bounds__(256) void k_qkv(
    const float* __restrict__ x,
    const float* __restrict__ wq, const float* __restrict__ bq,
    const float* __restrict__ wk, const float* __restrict__ bk,
    const float* __restrict__ wv, const float* __restrict__ bv,
    float* __restrict__ Q, float* __restrict__ K, float* __restrict__ V)
{
    __shared__ float xs[16][64];
    int tid = threadIdx.x;
    int t0 = blockIdx.x * 16;
    ((float4*)xs)[tid] = ((const float4*)(x + t0 * D))[tid];
    __syncthreads();

    int j = tid & 63, g = tid >> 6;
    int h = j >> 4, k = j & 15;
    int wbase = h * (D * DH) + k;

    float qa[4], ka[4], va[4];
#pragma unroll
    for (int i = 0; i < 4; ++i) { qa[i] = bq[j]; ka[i] = bk[j]; va[i] = bv[j]; }

#pragma unroll 8
    for (int d = 0; d < D; ++d) {
        float wqv = wq[wbase + d * DH];
        float wkv = wk[wbase + d * DH];
        float wvv = wv[wbase + d * DH];
#pragma unroll
        for (int i = 0; i < 4; ++i) {
            float xd = xs[g * 4 + i][d];
            qa[i] = fmaf(xd, wqv, qa[i]);
            ka[i] = fmaf(xd, wkv, ka[i]);
            va[i] = fmaf(xd, wvv, va[i]);
        }
    }
#pragma unroll
    for (int i = 0; i < 4; ++i) {
        int t = t0 + g * 4 + i;
        int b = t >> 11, s = t & (S - 1);
        int off = ((b * H + h) * S + s) * DH + k;
        Q[off] = qa[i] * 0.25f;   // fold 1/sqrt(16)
        K[off] = ka[i];
        V[off] = va[i];
    }
}

// ---------------------------------------------------------------- kernel 2
// Causal flash attention, lane-owns-row version.
// Block = (pair, 64-row block). 8 waves split the key range [0, kmax].
// K/V rows are wave-uniform -> scalar/broadcast loads, NO LDS staging.
// Online softmax in chunks of 8 keys, branch-free single rescale per chunk.
__global__ __launch_bounds__(512) void k_attn(
    const float* __restrict__ Q, const float* __restrict__ K,
    const float* __restrict__ V, float* __restrict__ A)
{
    __shared__ float part[8][64][18];   // m, sum, acc[16] per wave x row

    int tid = threadIdx.x;
    int lane = tid & 63;
    int w = __builtin_amdgcn_readfirstlane(tid >> 6);   // wave id, SGPR

    int pair = blockIdx.x & 15;                 // b*H+h
    int rblk = 31 - (blockIdx.x >> 4);          // longest blocks first
    int rbase = rblk * 64;
    int row = rbase + lane;

    const float4* q4 = (const float4*)(Q + (pair * S + row) * DH);
    float4 q0 = q4[0], q1 = q4[1], q2 = q4[2], q3 = q4[3];

    const float4* K4 = (const float4*)(K + pair * S * DH);
    const float4* V4 = (const float4*)(V + pair * S * DH);

    int nk = rbase + 64;            // keys 0..kmax, multiple of 64
    int len = nk >> 3;              // per-wave key count, multiple of 8
    int kbeg = w * len;
    int kend = kbeg + len;

    float m = -1e30f, sum = 0.f;
    float acc[16];
#pragma unroll
    for (int j = 0; j < 16; ++j) acc[j] = 0.f;

    for (int k0 = kbeg; k0 < kend; k0 += 8) {
        float s[8];
#pragma unroll
        for (int i = 0; i < 8; ++i) {
            int kk = k0 + i;
            float4 ka = K4[kk * 4 + 0], kb = K4[kk * 4 + 1];
            float4 kc = K4[kk * 4 + 2], kd = K4[kk * 4 + 3];
            float sd;
            sd  = q0.x * ka.x; sd = fmaf(q0.y, ka.y, sd); sd = fmaf(q0.z, ka.z, sd); sd = fmaf(q0.w, ka.w, sd);
            sd = fmaf(q1.x, kb.x, sd); sd = fmaf(q1.y, kb.y, sd); sd = fmaf(q1.z, kb.z, sd); sd = fmaf(q1.w, kb.w, sd);
            sd = fmaf(q2.x, kc.x, sd); sd = fmaf(q2.y, kc.y, sd); sd = fmaf(q2.z, kc.z, sd); sd = fmaf(q2.w, kc.w, sd);
            sd = fmaf(q3.x, kd.x, sd); sd = fmaf(q3.y, kd.y, sd); sd = fmaf(q3.z, kd.z, sd); sd = fmaf(q3.w, kd.w, sd);
            s[i] = (kk <= row) ? sd : -1e30f;
        }
        float mc = m;
#pragma unroll
        for (int i = 0; i < 8; ++i) mc = fmaxf(mc, s[i]);
        float scale = __expf(m - mc);
        m = mc;
        float p[8];
        float psum = 0.f;
#pragma unroll
        for (int i = 0; i < 8; ++i) { p[i] = __expf(s[i] - mc); psum += p[i]; }
        sum = fmaf(sum, scale, psum);
#pragma unroll
        for (int j = 0; j < 16; ++j) acc[j] *= scale;
#pragma unroll
        for (int i = 0; i < 8; ++i) {
            int kk = k0 + i;
            float4 va = V4[kk * 4 + 0], vb = V4[kk * 4 + 1];
            float4 vc = V4[kk * 4 + 2], vd = V4[kk * 4 + 3];
            float pi = p[i];
            acc[ 0] = fmaf(pi, va.x, acc[ 0]); acc[ 1] = fmaf(pi, va.y, acc[ 1]);
            acc[ 2] = fmaf(pi, va.z, acc[ 2]); acc[ 3] = fmaf(pi, va.w, acc[ 3]);
            acc[ 4] = fmaf(pi, vb.x, acc[ 4]); acc[ 5] = fmaf(pi, vb.y, acc[ 5]);
            acc[ 6] = fmaf(pi, vb.z, acc[ 6]); acc[ 7] = fmaf(pi, vb.w, acc[ 7]);
            acc[ 8] = fmaf(pi, vc.x, acc[ 8]); acc[ 9] = fmaf(pi, vc.y, acc[ 9]);
            acc[10] = fmaf(pi, vc.z, acc[10]); acc[11] = fmaf(pi, vc.w, acc[11]);
            acc[12] = fmaf(pi, vd.x, acc[12]); acc[13] = fmaf(pi, vd.y, acc[13]);
            acc[14] = fmaf(pi, vd.z, acc[14]); acc[15] = fmaf(pi, vd.w, acc[15]);
        }
    }

    // ---- store partial, then 3-round tree merge (8 -> 4 -> 2 -> 1)
    {
        float* pp = &part[w][lane][0];
        pp[0] = m; pp[1] = sum;
#pragma unroll
        for (int j = 0; j < 16; ++j) pp[2 + j] = acc[j];
    }
    __syncthreads();
#pragma unroll
    for (int st = 4; st >= 1; st >>= 1) {
        if (w < st) {
            const float* qq = &part[w + st][lane][0];
            float m2 = qq[0], s2 = qq[1];
            float M  = fmaxf(m, m2);
            float e1 = __expf(m - M), e2 = __expf(m2 - M);
            sum = sum * e1 + s2 * e2;
#pragma unroll
            for (int j = 0; j < 16; ++j)
                acc[j] = acc[j] * e1 + qq[2 + j] * e2;
            m = M;
            if (st > 1) {
                float* pp = &part[w][lane][0];
                pp[0] = m; pp[1] = sum;
#pragma unroll
                for (int j = 0; j < 16; ++j) pp[2 + j] = acc[j];
            }
        }
        __syncthreads();
    }

    if (w == 0) {
        float inv = 1.f / sum;
        int b = pair >> 2, h = pair & 3;
        float4* Ap = (float4*)(A + (b * S + row) * D + h * DH);
        float4 o0 = { acc[ 0] * inv, acc[ 1] * inv, acc[ 2] * inv, acc[ 3] * inv };
        float4 o1 = { acc[ 4] * inv, acc[ 5] * inv, acc[ 6] * inv, acc[ 7] * inv };
        float4 o2 = { acc[ 8] * inv, acc[ 9] * inv, acc[10] * inv, acc[11] * inv };
        float4 o3 = { acc[12] * inv, acc[13] * inv, acc[14] * inv, acc[15] * inv };
        Ap[0] = o0; Ap[1] = o1; Ap[2] = o2; Ap[3] = o3;
    }
}

// ---------------------------------------------------------------- kernel 3
// Out-projection + residual + LayerNorm1, 16 tokens per block.
__global__ __launch_bounds__(256) void k_oproj(
    const float* __restrict__ A, const float* __restrict__ x,
    const float* __restrict__ wo, const float* __restrict__ bo,
    const float* __restrict__ g1, const float* __restrict__ bb1,
    float* __restrict__ R1)
{
    __shared__ float as[16][64];
    int tid = threadIdx.x;
    int t0 = blockIdx.x * 16;
    ((float4*)as)[tid] = ((const float4*)(A + t0 * D))[tid];
    __syncthreads();

    int j = tid & 63, g = tid >> 6;
    float o[4];
#pragma unroll
    for (int i = 0; i < 4; ++i)
        o[i] = bo[j] + x[(t0 + g * 4 + i) * D + j];

#pragma unroll 8
    for (int d = 0; d < D; ++d) {
        float wv = wo[d * D + j];
#pragma unroll
        for (int i = 0; i < 4; ++i)
            o[i] = fmaf(as[g * 4 + i][d], wv, o[i]);
    }
    float gj = g1[j], bj = bb1[j];
#pragma unroll
    for (int i = 0; i < 4; ++i) {
        float mu  = wave_sum(o[i]) * (1.f / 64.f);
        float dif = o[i] - mu;
        float var = wave_sum(dif * dif) * (1.f / 64.f);
        R1[(t0 + g * 4 + i) * D + j] = dif * rsqrtf(var + 1e-5f) * gj + bj;
    }
}

// ---------------------------------------------------------------- kernel 4
// FFN + residual + LayerNorm2, 16 tokens per block.
__global__ __launch_bounds__(256) void k_ffn(
    const float* __restrict__ R1,
    const float* __restrict__ w1, const float* __restrict__ b1,
    const float* __restrict__ w2, const float* __restrict__ b2,
    const float* __restrict__ g2, const float* __restrict__ bb2,
    float* __restrict__ out)
{
    __shared__ float xr[16][64];      // 4 KB
    __shared__ float hh[256][20];     // 20 KB, padded stride 20 (conflict-free)
    int tid = threadIdx.x;
    int t0 = blockIdx.x * 16;
    ((float4*)xr)[tid] = ((const float4*)(R1 + t0 * D))[tid];
    __syncthreads();

    // stage 1: hidden f = tid for all 16 tokens
    float h[16];
#pragma unroll
    for (int t = 0; t < 16; ++t) h[t] = b1[tid];
#pragma unroll 8
    for (int d = 0; d < D; ++d) {
        float wv = w1[d * F + tid];
#pragma unroll
        for (int t = 0; t < 16; ++t)
            h[t] = fmaf(xr[t][d], wv, h[t]);
    }
#pragma unroll
    for (int t = 0; t < 16; t += 4) {
        float4 hv = { fmaxf(h[t], 0.f), fmaxf(h[t+1], 0.f),
                      fmaxf(h[t+2], 0.f), fmaxf(h[t+3], 0.f) };
        *(float4*)&hh[tid][t] = hv;
    }
    __syncthreads();

    // stage 2: output column j for tokens 4g..4g+3
    int j = tid & 63, g = tid >> 6;
    float y[4];
#pragma unroll
    for (int i = 0; i < 4; ++i)
        y[i] = b2[j] + xr[4 * g + i][j];
#pragma unroll 8
    for (int f = 0; f < F; ++f) {
        float wv = w2[f * D + j];
        float4 hv = *(const float4*)&hh[f][4 * g];
        y[0] = fmaf(hv.x, wv, y[0]);
        y[1] = fmaf(hv.y, wv, y[1]);
        y[2] = fmaf(hv.z, wv, y[2]);
        y[3] = fmaf(hv.w, wv, y[3]);
    }
    float gj = g2[j], bj = bb2[j];
#pragma unroll
    for (int i = 0; i < 4; ++i) {
        float mu  = wave_sum(y[i]) * (1.f / 64.f);
        float dif = y[i] - mu;
        float var = wave_sum(dif * dif) * (1.f / 64.f);
        out[(t0 + 4 * g + i) * D + j] = dif * rsqrtf(var + 1e-5f) * gj + bj;
    }
}

// ----------------------------------------------------------------
extern "C" void kernel_launch(void* const* d_in, const int* in_sizes, int n_in,
                              void* d_out, int out_size, void* d_ws, size_t ws_size,
                              hipStream_t stream)
{
    const float* x   = (const float*)d_in[0];
    const float* wq  = (const float*)d_in[1];
    const float* bq  = (const float*)d_in[2];
    const float* wk  = (const float*)d_in[3];
    const float* bk  = (const float*)d_in[4];
    const float* wv  = (const float*)d_in[5];
    const float* bv  = (const float*)d_in[6];
    const float* wo  = (const float*)d_in[7];
    const float* bo  = (const float*)d_in[8];
    const float* g1  = (const float*)d_in[9];
    const float* be1 = (const float*)d_in[10];
    const float* w1  = (const float*)d_in[11];
    const float* b1  = (const float*)d_in[12];
    const float* w2  = (const float*)d_in[13];
    const float* b2  = (const float*)d_in[14];
    const float* g2  = (const float*)d_in[15];
    const float* be2 = (const float*)d_in[16];

    float* ws = (float*)d_ws;
    float* Q  = ws;             // [B,H,S,16]
    float* K  = Q + T * DH * H; // [B,H,S,16]
    float* V  = K + T * DH * H; // [B,H,S,16]
    float* A  = V + T * DH * H; // [B,S,64]
    float* R1 = A + T * D;      // [B,S,64]

    k_qkv  <<<T / 16, 256, 0, stream>>>(x, wq, bq, wk, bk, wv, bv, Q, K, V);
    k_attn <<<(B * H) * (S / 64), 512, 0, stream>>>(Q, K, V, A);
    k_oproj<<<T / 16, 256, 0, stream>>>(A, x, wo, bo, g1, be1, R1);
    k_ffn  <<<T / 16, 256, 0, stream>>>(R1, w1, b1, w2, b2, g2, be2, (float*)d_out);
}